// Round 1
// baseline (222.978 us; speedup 1.0000x reference)
//
#include <hip/hip_runtime.h>

#define NB 32
#define NL 6
#define NR 8
#define NH 64
#define NTRAJ 262144   // 8^6
// out shape: (NB, NTRAJ, NL) fp32, flat idx = b*NTRAJ*NL + n*NL + l

// Kernel 1: q0[b][l][r] = W3[0] . relu(W2 @ relu(W1 @ [rp[l,r,0], phi[b,l]] + b1) + b2) + b3[0]
// One block (1 wave, 64 threads) per (b,l,r). 1536 blocks.
__global__ __launch_bounds__(64) void q0_kernel(
    const float* __restrict__ phi,   // (B, L)
    const float* __restrict__ rp,    // (L, R, 1)
    const float* __restrict__ W1,    // (H, 2)
    const float* __restrict__ b1,    // (H)
    const float* __restrict__ W2,    // (H, H)
    const float* __restrict__ b2,    // (H)
    const float* __restrict__ W3,    // (6, H) -> row 0
    const float* __restrict__ b3,    // (6)
    float* __restrict__ q0)          // (B, L, R) flat
{
    const int bid = blockIdx.x;      // = (b*NL + l)*NR + r
    const int r  = bid & 7;
    const int bl = bid >> 3;         // b*NL + l
    const int l  = bl % NL;
    const int h  = threadIdx.x;      // 0..63

    const float x = rp[l * NR + r];  // Z==1
    const float p = phi[bl];

    float h1 = fmaf(W1[h * 2 + 0], x, fmaf(W1[h * 2 + 1], p, b1[h]));
    h1 = fmaxf(h1, 0.0f);

    __shared__ float s_h1[NH];
    s_h1[h] = h1;
    __syncthreads();

    float acc = b2[h];
    const float* w2row = W2 + h * NH;
    #pragma unroll
    for (int k = 0; k < NH; ++k) acc = fmaf(w2row[k], s_h1[k], acc);
    const float h2 = fmaxf(acc, 0.0f);

    float v = W3[h] * h2;
    // wave-64 shuffle reduction
    #pragma unroll
    for (int off = 32; off > 0; off >>= 1)
        v += __shfl_down(v, off, 64);

    if (h == 0) q0[bid] = v + b3[0];
}

// Kernel 2: out[b][n][l] = q0[b][l][(n >> 3l) & 7].
// Thread handles n = 2t, 2t+1 (digits for l>=1 identical since n even -> no carry).
// Writes 12 consecutive floats = 3 aligned float4 stores.
// Grid: NB * (NTRAJ/2) / 256 = 16384 blocks of 256. 512 blocks per b.
__global__ __launch_bounds__(256) void scatter_kernel(
    const float* __restrict__ q0,    // (B, L, R)
    float* __restrict__ out)         // (B, NTRAJ, L)
{
    __shared__ float s[NL * NR];     // 48 floats for this block's b
    const int bid = blockIdx.x;
    const int b   = bid >> 9;        // 512 blocks per b
    const int tid = threadIdx.x;

    if (tid < NL * NR) s[tid] = q0[b * NL * NR + tid];
    __syncthreads();

    const int pair = ((bid & 511) << 8) | tid;   // 0 .. 131071
    const int n    = pair << 1;                  // even

    const float v0a = s[       (n       & 7)     ];  // l=0, n
    const float v0b = s[       (n       & 7) + 1 ];  // l=0, n+1
    const float v1  = s[ 8  + ((n >> 3 ) & 7)    ];
    const float v2  = s[16  + ((n >> 6 ) & 7)    ];
    const float v3  = s[24  + ((n >> 9 ) & 7)    ];
    const float v4  = s[32  + ((n >> 12) & 7)    ];
    const float v5  = s[40  + ((n >> 15) & 7)    ];

    float4* p = (float4*)(out + ((size_t)b * NTRAJ + (size_t)n) * NL);
    p[0] = make_float4(v0a, v1, v2, v3);
    p[1] = make_float4(v4, v5, v0b, v1);
    p[2] = make_float4(v2, v3, v4, v5);
}

extern "C" void kernel_launch(void* const* d_in, const int* in_sizes, int n_in,
                              void* d_out, int out_size, void* d_ws, size_t ws_size,
                              hipStream_t stream) {
    const float* phi = (const float*)d_in[0];  // (32, 6)
    const float* rp  = (const float*)d_in[1];  // (6, 8, 1)
    const float* W1  = (const float*)d_in[2];  // (64, 2)
    const float* b1  = (const float*)d_in[3];  // (64,)
    const float* W2  = (const float*)d_in[4];  // (64, 64)
    const float* b2  = (const float*)d_in[5];  // (64,)
    const float* W3  = (const float*)d_in[6];  // (6, 64)
    const float* b3  = (const float*)d_in[7];  // (6,)
    float* out = (float*)d_out;
    float* q0  = (float*)d_ws;                 // 1536 floats = 6 KB

    q0_kernel<<<NB * NL * NR, 64, 0, stream>>>(phi, rp, W1, b1, W2, b2, W3, b3, q0);

    const int nblocks = NB * (NTRAJ / 2) / 256; // 16384
    scatter_kernel<<<nblocks, 256, 0, stream>>>(q0, out);
}

// Round 2
// 206.938 us; speedup vs baseline: 1.0775x; 1.0775x over previous
//
#include <hip/hip_runtime.h>

#define NB 32
#define NL 6
#define NR 8
#define NH 64
#define NTRAJ 262144        // 8^6
#define F4_PER_B (NTRAJ * NL / 4)   // 393216 float4 per batch element
// out shape: (NB, NTRAJ, NL) fp32, flat idx = b*NTRAJ*NL + n*NL + l

// Kernel 1: q0[b][l][r] = W3[0] . relu(W2 @ relu(W1 @ [rp[l,r,0], phi[b,l]] + b1) + b2) + b3[0]
// One block (1 wave, 64 threads) per (b,l,r). 1536 blocks. ~microseconds.
__global__ __launch_bounds__(64) void q0_kernel(
    const float* __restrict__ phi,   // (B, L)
    const float* __restrict__ rp,    // (L, R, 1)
    const float* __restrict__ W1,    // (H, 2)
    const float* __restrict__ b1,    // (H)
    const float* __restrict__ W2,    // (H, H)
    const float* __restrict__ b2,    // (H)
    const float* __restrict__ W3,    // (6, H) -> row 0
    const float* __restrict__ b3,    // (6)
    float* __restrict__ q0)          // (B, L, R) flat
{
    const int bid = blockIdx.x;      // = (b*NL + l)*NR + r
    const int r  = bid & 7;
    const int bl = bid >> 3;         // b*NL + l
    const int l  = bl % NL;
    const int h  = threadIdx.x;      // 0..63

    const float x = rp[l * NR + r];  // Z==1
    const float p = phi[bl];

    float h1 = fmaf(W1[h * 2 + 0], x, fmaf(W1[h * 2 + 1], p, b1[h]));
    h1 = fmaxf(h1, 0.0f);

    __shared__ float s_h1[NH];
    s_h1[h] = h1;
    __syncthreads();

    float acc = b2[h];
    const float* w2row = W2 + h * NH;
    #pragma unroll
    for (int k = 0; k < NH; ++k) acc = fmaf(w2row[k], s_h1[k], acc);
    const float h2 = fmaxf(acc, 0.0f);

    float v = W3[h] * h2;
    // wave-64 shuffle reduction
    #pragma unroll
    for (int off = 32; off > 0; off >>= 1)
        v += __shfl_down(v, off, 64);

    if (h == 0) q0[bid] = v + b3[0];
}

// Kernel 2: out[b][n][l] = q0[b][l][(n >> 3l) & 7].
// One float4 store per thread at flat float4 index -> lane i writes base+16*i,
// perfectly coalesced full-line bursts (the old version had a 48B/lane stride,
// partial-line writes, ~2 TB/s; fillBuffer on the same buffer hits 6.5 TB/s).
// Every 3 float4 = 12 floats = trajectories {n=2k, 2k+1} (n even -> digit l>=1
// identical for n and n+1; d0 of n+1 is d0+1).
// Grid: (F4_PER_B/256, NB) = (1536, 32).
__global__ __launch_bounds__(256) void scatter_kernel(
    const float* __restrict__ q0,    // (B, L, R)
    float4* __restrict__ out4)       // (B, NTRAJ, L) viewed as float4
{
    __shared__ float s[NL * NR];     // 48 floats for this block's b
    const int b   = blockIdx.y;
    const int tid = threadIdx.x;

    if (tid < NL * NR) s[tid] = q0[b * NL * NR + tid];
    __syncthreads();

    const unsigned u = blockIdx.x * 256u + tid;   // float4 index within b, [0, 393216)
    const unsigned k = u / 3u;                    // pair index -> n = 2k (magic-mul)
    const unsigned m = u - 3u * k;                // position of this float4 in the 12-float group

    // digits of n = 2k:  d0 = (2k)&7 (even), d_l = (k >> (3l-1)) & 7 for l>=1
    const float2 v0 = ((const float2*)s)[k & 3u];        // s[d0], s[d0+1]
    const float  v1 = s[ 8 + ((k >>  2) & 7u)];
    const float  v2 = s[16 + ((k >>  5) & 7u)];
    const float  v3 = s[24 + ((k >>  8) & 7u)];
    const float  v4 = s[32 + ((k >> 11) & 7u)];
    const float  v5 = s[40 + ((k >> 14) & 7u)];

    // group layout: [v0a v1 v2 v3 | v4 v5 v0b v1 | v2 v3 v4 v5]
    float4 val;
    val.x = (m == 0) ? v0.x : ((m == 1) ? v4   : v2);
    val.y = (m == 0) ? v1   : ((m == 1) ? v5   : v3);
    val.z = (m == 0) ? v2   : ((m == 1) ? v0.y : v4);
    val.w = (m == 0) ? v3   : ((m == 1) ? v1   : v5);

    out4[(size_t)b * F4_PER_B + u] = val;
}

extern "C" void kernel_launch(void* const* d_in, const int* in_sizes, int n_in,
                              void* d_out, int out_size, void* d_ws, size_t ws_size,
                              hipStream_t stream) {
    const float* phi = (const float*)d_in[0];  // (32, 6)
    const float* rp  = (const float*)d_in[1];  // (6, 8, 1)
    const float* W1  = (const float*)d_in[2];  // (64, 2)
    const float* b1  = (const float*)d_in[3];  // (64,)
    const float* W2  = (const float*)d_in[4];  // (64, 64)
    const float* b2  = (const float*)d_in[5];  // (64,)
    const float* W3  = (const float*)d_in[6];  // (6, 64)
    const float* b3  = (const float*)d_in[7];  // (6,)
    float* out = (float*)d_out;
    float* q0  = (float*)d_ws;                 // 1536 floats = 6 KB

    q0_kernel<<<NB * NL * NR, 64, 0, stream>>>(phi, rp, W1, b1, W2, b2, W3, b3, q0);

    dim3 grid(F4_PER_B / 256, NB);
    scatter_kernel<<<grid, 256, 0, stream>>>(q0, (float4*)out);
}